// Round 20
// baseline (358.358 us; speedup 1.0000x reference)
//
#include <hip/hip_runtime.h>

#define NN 50000
#define NE 800000
#define HID 128
#define KEYSZ 32
#define NB 196   // ceil(NN/256)
#define RBK 391  // ceil(NN/128)

typedef __attribute__((ext_vector_type(8))) short bf16x8;
typedef __attribute__((ext_vector_type(4))) float f32x4;

__device__ inline unsigned short f2bf(float f) {
    unsigned int b = __float_as_uint(f);
    unsigned int r = (b + 0x7FFF + ((b >> 16) & 1)) >> 16;
    return (unsigned short)r;
}
__device__ inline float bf2f(unsigned short u) {
    return __uint_as_float(((unsigned int)u) << 16);
}

__device__ __forceinline__ void gload16(const unsigned short* g, unsigned short* l) {
    __builtin_amdgcn_global_load_lds(
        (const __attribute__((address_space(1))) unsigned int*)g,
        (__attribute__((address_space(3))) unsigned int*)l, 16, 0, 0);
}

// ---- merged prep: vsq weights | gru weights | x,h -> bf16 | count_deg (deg pre-zeroed) ----
__global__ void prep_all(const float* __restrict__ Wv, const float* __restrict__ Ws,
                         const float* __restrict__ Wq, const float* __restrict__ bv,
                         const float* __restrict__ bs, const float* __restrict__ bq,
                         const float* __restrict__ Wih, const float* __restrict__ bih,
                         const float* __restrict__ Whh, const float* __restrict__ bhh,
                         const float* __restrict__ x, const float* __restrict__ h0,
                         const int* __restrict__ dst,
                         unsigned short* __restrict__ Bvsq, float* __restrict__ biasv,
                         unsigned short* __restrict__ Bgru, float* __restrict__ biasg,
                         unsigned short* __restrict__ xbf, unsigned short* __restrict__ hbf,
                         int* __restrict__ deg) {
    int t = blockIdx.x * 256 + threadIdx.x;
    if (t < 256 * 256) {
        if (t < 256)
            biasv[t] = (t < 128) ? bv[t] : (t < 160) ? bs[t - 128]
                     : (t < 192) ? bq[t - 160] : 0.f;
        int m = t >> 8, k = t & 255;
        float w = (m < 128) ? Wv[k * 128 + m]
                : (m < 160) ? Ws[k * 32 + (m - 128)]
                : (m < 192) ? Wq[k * 32 + (m - 160)]
                            : 0.f;
        Bvsq[m * 256 + k] = f2bf(w);
        return;
    }
    t -= 256 * 256;
    if (t < 512 * 384) {
        if (t < 512)
            biasg[t] = (t < 256) ? bih[t] + bhh[t] : (t < 384) ? bih[t] : bhh[t - 128];
        int m = t / 384, k = t - m * 384;
        float w = 0.f;
        if (m < 256) w = (k < 256) ? Wih[m * 256 + k] : Whh[m * 128 + (k - 256)];
        else if (m < 384) { if (k < 256) w = Wih[m * 256 + k]; }
        else { if (k >= 256) w = Whh[(m - 128) * 128 + (k - 256)]; }
        Bgru[t] = f2bf(w);
        return;
    }
    t -= 512 * 384;
    if (t < 2 * NN * 16) {
        const float* src = (t < NN * 16) ? x : h0;
        unsigned short* dstp = (t < NN * 16) ? xbf : hbf;
        int i = (t < NN * 16) ? t : t - NN * 16;
        const float4* p = reinterpret_cast<const float4*>(src) + (size_t)i * 2;
        float4 a = p[0], b = p[1];
        uint4 o;
        o.x = (unsigned int)f2bf(a.x) | ((unsigned int)f2bf(a.y) << 16);
        o.y = (unsigned int)f2bf(a.z) | ((unsigned int)f2bf(a.w) << 16);
        o.z = (unsigned int)f2bf(b.x) | ((unsigned int)f2bf(b.y) << 16);
        o.w = (unsigned int)f2bf(b.z) | ((unsigned int)f2bf(b.w) << 16);
        reinterpret_cast<uint4*>(dstp)[i] = o;
        return;
    }
    t -= 2 * NN * 16;
    if (t < NE) atomicAdd(&deg[dst[t]], 1);
}
#define PREP_TOTAL (256 * 256 + 512 * 384 + 2 * NN * 16 + NE)

// ---------------- CSR scan ----------------
__global__ __launch_bounds__(256) void part_kernel(const int* __restrict__ deg,
                                                   int* __restrict__ part) {
    int i = blockIdx.x * 256 + threadIdx.x;
    int v = (i < NN) ? deg[i] : 0;
#pragma unroll
    for (int o = 32; o > 0; o >>= 1) v += __shfl_xor(v, o);
    __shared__ int w[4];
    if ((threadIdx.x & 63) == 0) w[threadIdx.x >> 6] = v;
    __syncthreads();
    if (threadIdx.x == 0) part[blockIdx.x] = w[0] + w[1] + w[2] + w[3];
}
__global__ __launch_bounds__(256) void scanp_kernel(const int* __restrict__ part,
                                                    int* __restrict__ boff,
                                                    int* __restrict__ rowp) {
    __shared__ int s[256];
    int t = threadIdx.x;
    int v = (t < NB) ? part[t] : 0;
    s[t] = v;
    __syncthreads();
    for (int o = 1; o < 256; o <<= 1) {
        int u = (t >= o) ? s[t - o] : 0;
        __syncthreads();
        s[t] += u;
        __syncthreads();
    }
    if (t < NB) boff[t] = s[t] - v;
    if (t == NB - 1) rowp[NN] = s[t];
}
__global__ __launch_bounds__(256) void scan3_kernel(const int* __restrict__ deg,
                                                    const int* __restrict__ boff,
                                                    int* __restrict__ rowp,
                                                    int* __restrict__ cursor) {
    __shared__ int s[256];
    int t = threadIdx.x;
    int i = blockIdx.x * 256 + t;
    int v = (i < NN) ? deg[i] : 0;
    s[t] = v;
    __syncthreads();
    for (int o = 1; o < 256; o <<= 1) {
        int u = (t >= o) ? s[t - o] : 0;
        __syncthreads();
        s[t] += u;
        __syncthreads();
    }
    if (i < NN) {
        int r = boff[blockIdx.x] + s[t] - v;
        rowp[i] = r;
        cursor[i] = r;
    }
}

// ---------------- MFMA GEMM body (128x128 tile, 8-wave, gload_lds dbuf 2-phase) ----------------
// Explicit (rb, cb, kbeg, kend); caller computes mapping/swizzle.
// mode 2 (vsq): col<128 -> Cb1[n*128+col] ; 128<=col<192 -> Cb2[n*64+col-128]
// mode 3 (gru): col<384 -> Cb1[n*384+col] ; col>=384 -> Cb2[n*128+col-384]
__device__ __forceinline__ void gemm_body(
    const unsigned short* __restrict__ A0, const unsigned short* __restrict__ A1,
    const unsigned short* __restrict__ A2, const unsigned short* __restrict__ Bt,
    const float* __restrict__ bias, unsigned short* __restrict__ Cb1,
    unsigned short* __restrict__ Cb2, int Kstride, int Nrows, int mode,
    int rb, int cb, int kbeg, int kend) {
    __shared__ unsigned short As[2][128 * 32];
    __shared__ unsigned short Bs[2][128 * 32];
    const int tid = threadIdx.x;
    const int lane = tid & 63;
    const int wave = tid >> 6;          // 0..7
    const int wm = wave >> 2, wn = wave & 3;

    const int q0 = wave * 64 + lane;
    const int ar0 = q0 >> 2;
    const int ac0 = ((q0 & 3) ^ ((ar0 >> 1) & 3)) * 8;
    const size_t aoff0 = (size_t)min(rb + ar0, Nrows - 1) * 128 + ac0;
    const size_t boff0 = (size_t)(cb + ar0) * Kstride + ac0;
    const int ldsc0 = (wave * 64) * 8;

#define STAGE(buf, k0s) do {                                              \
        const unsigned short* Ak_ = ((k0s) < 128) ? A0                    \
                                  : ((k0s) < 256) ? A1 : A2;              \
        const int kk_ = (k0s) & 127;                                      \
        gload16(Ak_ + aoff0 + kk_, &As[buf][ldsc0]);                      \
        gload16(Bt + boff0 + (k0s), &Bs[buf][ldsc0]);                     \
    } while (0)

    f32x4 acc[4][2];
#pragma unroll
    for (int i = 0; i < 4; i++)
#pragma unroll
        for (int j = 0; j < 2; j++)
#pragma unroll
            for (int r = 0; r < 4; r++) acc[i][j][r] = 0.f;

    const int r16 = lane & 15;
    const int cof = (((lane >> 4) ^ ((r16 >> 1) & 3)) * 8);

    STAGE(0, kbeg);
    __syncthreads();
    int cur = 0;
    for (int k0 = kbeg; k0 < kend; k0 += 32) {
        if (k0 + 32 < kend) STAGE(cur ^ 1, k0 + 32);
        bf16x8 af[4], bfr[2];
#pragma unroll
        for (int rt = 0; rt < 4; rt++)
            af[rt] = *reinterpret_cast<const bf16x8*>(
                &As[cur][(wm * 64 + rt * 16 + r16) * 32 + cof]);
#pragma unroll
        for (int ct = 0; ct < 2; ct++)
            bfr[ct] = *reinterpret_cast<const bf16x8*>(
                &Bs[cur][(wn * 32 + ct * 16 + r16) * 32 + cof]);
#pragma unroll
        for (int rt = 0; rt < 4; rt++)
#pragma unroll
            for (int ct = 0; ct < 2; ct++)
                acc[rt][ct] = __builtin_amdgcn_mfma_f32_16x16x32_bf16(af[rt], bfr[ct], acc[rt][ct], 0, 0, 0);
        __syncthreads();
        cur ^= 1;
    }
#undef STAGE

#pragma unroll
    for (int rt = 0; rt < 4; rt++) {
#pragma unroll
        for (int ct = 0; ct < 2; ct++) {
            int col = cb + wn * 32 + ct * 16 + r16;
            float bv = bias[col];
#pragma unroll
            for (int r = 0; r < 4; r++) {
                int row = rb + wm * 64 + rt * 16 + (lane >> 4) * 4 + r;
                if (row < Nrows) {
                    float v = acc[rt][ct][r] + bv;
                    if (mode == 2) {
                        if (col < 128) Cb1[(size_t)row * 128 + col] = f2bf(v);
                        else if (col < 192) Cb2[(size_t)row * 64 + (col - 128)] = f2bf(v);
                    } else {
                        if (col < 384) Cb1[(size_t)row * 384 + col] = f2bf(v);
                        else Cb2[(size_t)row * 128 + (col - 384)] = f2bf(v);
                    }
                }
            }
        }
    }
}

__device__ __forceinline__ int swz_nid(int wg, int swzq, int swzr) {
    int xcd = wg & 7, pos = wg >> 3;
    return (xcd < swzr) ? xcd * (swzq + 1) + pos
                        : swzr * (swzq + 1) + (xcd - swzr) * swzq + pos;
}

// mode 2: vsq (nid -> rb x {0,128}); mode 3: gru cols 0..383 only (nid -> rb x {0,128,256})
__global__ __launch_bounds__(512) void gemm_kernel(
    const unsigned short* __restrict__ A0, const unsigned short* __restrict__ A1,
    const unsigned short* __restrict__ A2, const unsigned short* __restrict__ Bt,
    const float* __restrict__ bias, unsigned short* __restrict__ Cb1,
    unsigned short* __restrict__ Cb2, int Kstride, int Nrows, int mode,
    int swzq, int swzr) {
    int nid = swz_nid(blockIdx.x, swzq, swzr);
    int rb, cb, kbeg, kend;
    if (mode == 2) {
        rb = (nid >> 1) * 128; cb = (nid & 1) * 128; kbeg = 0; kend = 256;
    } else {
        int c3 = nid % 3;
        rb = (nid / 3) * 128; cb = c3 * 128;
        kbeg = 0; kend = (c3 == 2) ? 256 : 384;
    }
    gemm_body(A0, A1, A2, Bt, bias, Cb1, Cb2, Kstride, Nrows, mode, rb, cb, kbeg, kend);
}

// ---- fused round-0 kernel: gemmV + scatter INTERLEAVED 1:2 (co-resident), then fill ----
#define SCAT_B ((NE + 511) / 512)
#define FILL_B ((NN + 7) / 8)
__global__ __launch_bounds__(512) void gemmv_fused(
    const unsigned short* __restrict__ xbf, const unsigned short* __restrict__ hbf,
    const unsigned short* __restrict__ Bvsq, const float* __restrict__ biasv,
    unsigned short* __restrict__ vbf, unsigned short* __restrict__ sqbf,
    int Nrows, int swzq, int swzr, int nwgv,
    const int* __restrict__ src, const int* __restrict__ dst,
    int* __restrict__ cursor, int* __restrict__ ssort,
    const int* __restrict__ rowp, int* __restrict__ dsort) {
    int bid = blockIdx.x;
    const int T = nwgv + SCAT_B;
    if (bid < T) {
        int g = bid / 3, r = bid - g * 3;
        if (r == 0 && g < nwgv) {
            int nid = swz_nid(g, swzq, swzr);
            gemm_body(xbf, hbf, hbf, Bvsq, biasv, vbf, sqbf, 256, Nrows, 2,
                      (nid >> 1) * 128, (nid & 1) * 128, 0, 256);
            return;
        }
        int sidx = bid - ((g < nwgv) ? (g + (r > 0 ? 1 : 0)) : nwgv);
        int i = sidx * 512 + threadIdx.x;
        if (i < NE) {
            int d = dst[i];
            int slot = atomicAdd(&cursor[d], 1);
            ssort[slot] = src[i];
        }
        return;
    }
    bid -= T;
    int node = bid * 8 + (threadIdx.x >> 6);
    if (node >= NN) return;
    int lane = threadIdx.x & 63;
    int beg = rowp[node], end = rowp[node + 1];
    for (int i = beg + lane; i < end; i += 64) dsort[i] = node;
}

// ---------------- edge dot (bf16 s,q) ----------------
__global__ void edot_kernel(const unsigned short* __restrict__ sqbf,
                            const int* __restrict__ ss, const int* __restrict__ ds,
                            float* __restrict__ eo) {
    int i = blockIdx.x * 256 + threadIdx.x;
    if (i >= NE) return;
    const unsigned short* s = sqbf + (size_t)ss[i] * 64;       // dims 0..31 = sig
    const unsigned short* q = sqbf + (size_t)ds[i] * 64 + 32;  // dims 32..63 = que
    float acc = 0.f;
#pragma unroll
    for (int j = 0; j < 4; j++) {
        uint4 a = reinterpret_cast<const uint4*>(s)[j];
        uint4 b = reinterpret_cast<const uint4*>(q)[j];
        const unsigned int* ap = reinterpret_cast<const unsigned int*>(&a);
        const unsigned int* bp = reinterpret_cast<const unsigned int*>(&b);
#pragma unroll
        for (int w = 0; w < 4; w++) {
            acc += bf2f(ap[w] & 0xffff) * bf2f(bp[w] & 0xffff);
            acc += bf2f(ap[w] >> 16) * bf2f(bp[w] >> 16);
        }
    }
    eo[i] = acc * (1.0f / KEYSZ);
}

// ---- fused aggregate + hn-GEMM (gemmG col-block 3 depends only on h -> overlap) ----
// Every 17th block is an hn gemm block (MFMA); the rest run the proven 16x4 aggregate
// (memory-latency-bound) with 8 nodes per 512-thread block. Complementary pipes.
__global__ __launch_bounds__(512) void agg_fused(
    const unsigned short* __restrict__ vbf, float* __restrict__ es,
    const int* __restrict__ ssort, const int* __restrict__ rowp,
    unsigned short* __restrict__ cbf,
    const unsigned short* __restrict__ xbf, const unsigned short* __restrict__ hbf,
    const unsigned short* __restrict__ Bgru, const float* __restrict__ biasg,
    unsigned short* __restrict__ hnbf, int Nrows) {
    int bid = blockIdx.x;
    int g = bid / 17, r = bid - g * 17;
    if (r == 16 && g < RBK) {
        gemm_body(xbf, nullptr, hbf, Bgru, biasg, nullptr, hnbf, 384, Nrows, 3,
                  g * 128, 384, 256, 384);
        return;
    }
    int aidx = bid - min(g + (r == 16 ? 1 : 0), RBK);
    int node = aidx * 8 + (threadIdx.x >> 6);
    if (node >= NN) return;
    int lane = threadIdx.x & 63;
    int beg = rowp[node], end = rowp[node + 1];
    if (beg == end) {
        reinterpret_cast<unsigned int*>(cbf + (size_t)node * 128)[lane] = 0u;
        return;
    }
    float m = -1e30f;
    for (int i = beg + lane; i < end; i += 64) m = fmaxf(m, es[i]);
#pragma unroll
    for (int o = 32; o > 0; o >>= 1) m = fmaxf(m, __shfl_xor(m, o));
    float d = 0.f;
    for (int i = beg + lane; i < end; i += 64) {
        float e = __expf(es[i] - m);
        es[i] = e;
        d += e;
    }
#pragma unroll
    for (int o = 32; o > 0; o >>= 1) d += __shfl_xor(d, o);
    float inv = 1.0f / d;
    const int gg = lane >> 4, rr = lane & 15;
    float a[8];
#pragma unroll
    for (int k = 0; k < 8; k++) a[k] = 0.f;
#pragma unroll 2
    for (int c0 = beg; c0 < end; c0 += 4) {
        int idx = c0 + gg;
        if (idx < end) {
            int sj = ssort[idx];
            float w = es[idx] * inv;
            uint4 uv = *reinterpret_cast<const uint4*>(vbf + (size_t)sj * 128 + rr * 8);
            a[0] += w * bf2f(uv.x & 0xffff);
            a[1] += w * bf2f(uv.x >> 16);
            a[2] += w * bf2f(uv.y & 0xffff);
            a[3] += w * bf2f(uv.y >> 16);
            a[4] += w * bf2f(uv.z & 0xffff);
            a[5] += w * bf2f(uv.z >> 16);
            a[6] += w * bf2f(uv.w & 0xffff);
            a[7] += w * bf2f(uv.w >> 16);
        }
    }
#pragma unroll
    for (int k = 0; k < 8; k++) {
        a[k] += __shfl_xor(a[k], 16);
        a[k] += __shfl_xor(a[k], 32);
    }
    if (gg == 0) {
        uint4 o;
        o.x = (unsigned int)f2bf(a[0]) | ((unsigned int)f2bf(a[1]) << 16);
        o.y = (unsigned int)f2bf(a[2]) | ((unsigned int)f2bf(a[3]) << 16);
        o.z = (unsigned int)f2bf(a[4]) | ((unsigned int)f2bf(a[5]) << 16);
        o.w = (unsigned int)f2bf(a[6]) | ((unsigned int)f2bf(a[7]) << 16);
        *reinterpret_cast<uint4*>(cbf + (size_t)node * 128 + rr * 8) = o;
    }
}
#define AGG_TOTAL (RBK * 17)

// ---------------- GRU elementwise (bf16 h in-place; f32 out only on final round) ----------------
__global__ void gru_kernel(const unsigned short* __restrict__ g,
                           const unsigned short* __restrict__ hn,
                           unsigned short* __restrict__ hio, float* __restrict__ fout) {
    int t = blockIdx.x * 256 + threadIdx.x;
    if (t >= NN * 64) return;
    int n = t >> 6, j2 = (t & 63) * 2;
    const unsigned short* grow = g + (size_t)n * 384;
    unsigned int ur = *reinterpret_cast<const unsigned int*>(grow + j2);
    unsigned int uz = *reinterpret_cast<const unsigned int*>(grow + 128 + j2);
    unsigned int un = *reinterpret_cast<const unsigned int*>(grow + 256 + j2);
    unsigned int uh = *reinterpret_cast<const unsigned int*>(hn + (size_t)n * 128 + j2);
    unsigned int uho = *reinterpret_cast<const unsigned int*>(hio + (size_t)n * 128 + j2);
    float ho0 = bf2f(uho & 0xffff), ho1 = bf2f(uho >> 16);
    float r0 = 1.f / (1.f + __expf(-bf2f(ur & 0xffff)));
    float r1 = 1.f / (1.f + __expf(-bf2f(ur >> 16)));
    float z0 = 1.f / (1.f + __expf(-bf2f(uz & 0xffff)));
    float z1 = 1.f / (1.f + __expf(-bf2f(uz >> 16)));
    float nx0 = bf2f(un & 0xffff) + r0 * bf2f(uh & 0xffff);
    float nx1 = bf2f(un >> 16) + r1 * bf2f(uh >> 16);
    float ng0 = 1.f - 2.f / (__expf(2.f * nx0) + 1.f);
    float ng1 = 1.f - 2.f / (__expf(2.f * nx1) + 1.f);
    float h0 = (1.f - z0) * ng0 + z0 * ho0;
    float h1 = (1.f - z1) * ng1 + z1 * ho1;
    *reinterpret_cast<unsigned int*>(hio + (size_t)n * 128 + j2) =
        (unsigned int)f2bf(h0) | ((unsigned int)f2bf(h1) << 16);
    if (fout)
        *reinterpret_cast<float2*>(fout + (size_t)n * 128 + j2) = make_float2(h0, h1);
}

extern "C" void kernel_launch(void* const* d_in, const int* in_sizes, int n_in,
                              void* d_out, int out_size, void* d_ws, size_t ws_size,
                              hipStream_t stream) {
    const float* x   = (const float*)d_in[0];
    const float* h0  = (const float*)d_in[1];
    const int* src   = (const int*)d_in[2];
    const int* dst   = (const int*)d_in[3];
    const float* Wv  = (const float*)d_in[4];
    const float* bv  = (const float*)d_in[5];
    const float* Wsg = (const float*)d_in[6];
    const float* bsg = (const float*)d_in[7];
    const float* Wq  = (const float*)d_in[8];
    const float* bq  = (const float*)d_in[9];
    const float* Wih = (const float*)d_in[10];
    const float* bih = (const float*)d_in[11];
    const float* Whh = (const float*)d_in[12];
    const float* bhh = (const float*)d_in[13];

    char* ws = (char*)d_ws;
    size_t off = 0;
    auto alloc = [&](size_t bytes) {
        void* p = ws + off;
        off = (off + bytes + 255) & ~(size_t)255;
        return p;
    };
    // region1: vbf[N][128]+sqbf[N][64] (bf16) during attention; gout[N][384] (bf16) after
    unsigned short* vbf = (unsigned short*)alloc((size_t)NN * 384 * 2);
    unsigned short* sqbf = vbf + (size_t)NN * 128;
    unsigned short* gout = vbf;
    float* es = (float*)alloc((size_t)NE * 4);
    int* deg = (int*)alloc(NN * 4);
    int* rowp = (int*)alloc((NN + 1) * 4);
    int* cur = (int*)alloc(NN * 4);
    int* part = (int*)alloc(NB * 4);
    int* boff = (int*)alloc(NB * 4);
    int* ssort = (int*)alloc((size_t)NE * 4);
    int* dsort = (int*)alloc((size_t)NE * 4);
    unsigned short* xbf = (unsigned short*)alloc((size_t)NN * 128 * 2);
    unsigned short* hbf = (unsigned short*)alloc((size_t)NN * 128 * 2);   // h, bf16, in-place
    unsigned short* cnbf = (unsigned short*)alloc((size_t)NN * 128 * 2);  // c (bf16)
    unsigned short* hnbf = (unsigned short*)alloc((size_t)NN * 128 * 2);  // hn (bf16)
    unsigned short* Bvsq = (unsigned short*)alloc(256 * 256 * 2);
    unsigned short* Bgru = (unsigned short*)alloc(512 * 384 * 2);
    float* biasv = (float*)alloc(256 * 4);
    float* biasg = (float*)alloc(512 * 4);

    const int NWG_V = RBK * 2, Q_V = NWG_V / 8, R_V = NWG_V % 8;
    const int NWG_G3 = RBK * 3, Q_G3 = NWG_G3 / 8, R_G3 = NWG_G3 % 8;

    hipMemsetAsync(deg, 0, NN * 4, stream);
    prep_all<<<(PREP_TOTAL + 255) / 256, 256, 0, stream>>>(
        Wv, Wsg, Wq, bv, bsg, bq, Wih, bih, Whh, bhh, x, h0, dst,
        Bvsq, biasv, Bgru, biasg, xbf, hbf, deg);
    part_kernel<<<NB, 256, 0, stream>>>(deg, part);
    scanp_kernel<<<1, 256, 0, stream>>>(part, boff, rowp);
    scan3_kernel<<<NB, 256, 0, stream>>>(deg, boff, rowp, cur);

    // round 0: gemmV interleaved with CSR scatter (+ dsort fill tail)
    gemmv_fused<<<NWG_V + SCAT_B + FILL_B, 512, 0, stream>>>(
        xbf, hbf, Bvsq, biasv, vbf, sqbf, NN, Q_V, R_V, NWG_V,
        src, dst, cur, ssort, rowp, dsort);
    edot_kernel<<<(NE + 255) / 256, 256, 0, stream>>>(sqbf, ssort, dsort, es);
    agg_fused<<<AGG_TOTAL, 512, 0, stream>>>(vbf, es, ssort, rowp, cnbf,
                                             xbf, hbf, Bgru, biasg, hnbf, NN);
    gemm_kernel<<<NWG_G3, 512, 0, stream>>>(xbf, cnbf, hbf, Bgru, biasg, gout, hnbf,
                                            384, NN, 3, Q_G3, R_G3);
    gru_kernel<<<(NN * 64 + 255) / 256, 256, 0, stream>>>(gout, hnbf, hbf, nullptr);

    // round 1
    gemm_kernel<<<NWG_V, 512, 0, stream>>>(xbf, hbf, hbf, Bvsq, biasv, vbf, sqbf,
                                           256, NN, 2, Q_V, R_V);
    edot_kernel<<<(NE + 255) / 256, 256, 0, stream>>>(sqbf, ssort, dsort, es);
    agg_fused<<<AGG_TOTAL, 512, 0, stream>>>(vbf, es, ssort, rowp, cnbf,
                                             xbf, hbf, Bgru, biasg, hnbf, NN);
    gemm_kernel<<<NWG_G3, 512, 0, stream>>>(xbf, cnbf, hbf, Bgru, biasg, gout, hnbf,
                                            384, NN, 3, Q_G3, R_G3);
    gru_kernel<<<(NN * 64 + 255) / 256, 256, 0, stream>>>(gout, hnbf, hbf, (float*)d_out);
}

// Round 21
// 335.945 us; speedup vs baseline: 1.0667x; 1.0667x over previous
//
#include <hip/hip_runtime.h>

#define NN 50000
#define NE 800000
#define HID 128
#define KEYSZ 32
#define NB 196  // ceil(NN/256)

typedef __attribute__((ext_vector_type(8))) short bf16x8;
typedef __attribute__((ext_vector_type(4))) float f32x4;

__device__ inline unsigned short f2bf(float f) {
    unsigned int b = __float_as_uint(f);
    unsigned int r = (b + 0x7FFF + ((b >> 16) & 1)) >> 16;
    return (unsigned short)r;
}
__device__ inline float bf2f(unsigned short u) {
    return __uint_as_float(((unsigned int)u) << 16);
}

__device__ __forceinline__ void gload16(const unsigned short* g, unsigned short* l) {
    __builtin_amdgcn_global_load_lds(
        (const __attribute__((address_space(1))) unsigned int*)g,
        (__attribute__((address_space(3))) unsigned int*)l, 16, 0, 0);
}

// ---- merged prep: vsq weights | gru weights | x,h -> bf16 | count_deg (deg pre-zeroed) ----
__global__ void prep_all(const float* __restrict__ Wv, const float* __restrict__ Ws,
                         const float* __restrict__ Wq, const float* __restrict__ bv,
                         const float* __restrict__ bs, const float* __restrict__ bq,
                         const float* __restrict__ Wih, const float* __restrict__ bih,
                         const float* __restrict__ Whh, const float* __restrict__ bhh,
                         const float* __restrict__ x, const float* __restrict__ h0,
                         const int* __restrict__ dst,
                         unsigned short* __restrict__ Bvsq, float* __restrict__ biasv,
                         unsigned short* __restrict__ Bgru, float* __restrict__ biasg,
                         unsigned short* __restrict__ xbf, unsigned short* __restrict__ hbf,
                         int* __restrict__ deg) {
    int t = blockIdx.x * 256 + threadIdx.x;
    if (t < 256 * 256) {
        if (t < 256)
            biasv[t] = (t < 128) ? bv[t] : (t < 160) ? bs[t - 128]
                     : (t < 192) ? bq[t - 160] : 0.f;
        int m = t >> 8, k = t & 255;
        float w = (m < 128) ? Wv[k * 128 + m]
                : (m < 160) ? Ws[k * 32 + (m - 128)]
                : (m < 192) ? Wq[k * 32 + (m - 160)]
                            : 0.f;
        Bvsq[m * 256 + k] = f2bf(w);
        return;
    }
    t -= 256 * 256;
    if (t < 512 * 384) {
        if (t < 512)
            biasg[t] = (t < 256) ? bih[t] + bhh[t] : (t < 384) ? bih[t] : bhh[t - 128];
        int m = t / 384, k = t - m * 384;
        float w = 0.f;
        if (m < 256) w = (k < 256) ? Wih[m * 256 + k] : Whh[m * 128 + (k - 256)];
        else if (m < 384) { if (k < 256) w = Wih[m * 256 + k]; }
        else { if (k >= 256) w = Whh[(m - 128) * 128 + (k - 256)]; }
        Bgru[t] = f2bf(w);
        return;
    }
    t -= 512 * 384;
    if (t < 2 * NN * 16) {
        const float* src = (t < NN * 16) ? x : h0;
        unsigned short* dstp = (t < NN * 16) ? xbf : hbf;
        int i = (t < NN * 16) ? t : t - NN * 16;
        const float4* p = reinterpret_cast<const float4*>(src) + (size_t)i * 2;
        float4 a = p[0], b = p[1];
        uint4 o;
        o.x = (unsigned int)f2bf(a.x) | ((unsigned int)f2bf(a.y) << 16);
        o.y = (unsigned int)f2bf(a.z) | ((unsigned int)f2bf(a.w) << 16);
        o.z = (unsigned int)f2bf(b.x) | ((unsigned int)f2bf(b.y) << 16);
        o.w = (unsigned int)f2bf(b.z) | ((unsigned int)f2bf(b.w) << 16);
        reinterpret_cast<uint4*>(dstp)[i] = o;
        return;
    }
    t -= 2 * NN * 16;
    if (t < NE) atomicAdd(&deg[dst[t]], 1);
}
#define PREP_TOTAL (256 * 256 + 512 * 384 + 2 * NN * 16 + NE)

// ---------------- CSR scan ----------------
__global__ __launch_bounds__(256) void part_kernel(const int* __restrict__ deg,
                                                   int* __restrict__ part) {
    int i = blockIdx.x * 256 + threadIdx.x;
    int v = (i < NN) ? deg[i] : 0;
#pragma unroll
    for (int o = 32; o > 0; o >>= 1) v += __shfl_xor(v, o);
    __shared__ int w[4];
    if ((threadIdx.x & 63) == 0) w[threadIdx.x >> 6] = v;
    __syncthreads();
    if (threadIdx.x == 0) part[blockIdx.x] = w[0] + w[1] + w[2] + w[3];
}
__global__ __launch_bounds__(256) void scanp_kernel(const int* __restrict__ part,
                                                    int* __restrict__ boff,
                                                    int* __restrict__ rowp) {
    __shared__ int s[256];
    int t = threadIdx.x;
    int v = (t < NB) ? part[t] : 0;
    s[t] = v;
    __syncthreads();
    for (int o = 1; o < 256; o <<= 1) {
        int u = (t >= o) ? s[t - o] : 0;
        __syncthreads();
        s[t] += u;
        __syncthreads();
    }
    if (t < NB) boff[t] = s[t] - v;
    if (t == NB - 1) rowp[NN] = s[t];
}
__global__ __launch_bounds__(256) void scan3_kernel(const int* __restrict__ deg,
                                                    const int* __restrict__ boff,
                                                    int* __restrict__ rowp,
                                                    int* __restrict__ cursor) {
    __shared__ int s[256];
    int t = threadIdx.x;
    int i = blockIdx.x * 256 + t;
    int v = (i < NN) ? deg[i] : 0;
    s[t] = v;
    __syncthreads();
    for (int o = 1; o < 256; o <<= 1) {
        int u = (t >= o) ? s[t - o] : 0;
        __syncthreads();
        s[t] += u;
        __syncthreads();
    }
    if (i < NN) {
        int r = boff[blockIdx.x] + s[t] - v;
        rowp[i] = r;
        cursor[i] = r;
    }
}

// ---------------- MFMA GEMM body (128x128 tile, 8-wave, gload_lds dbuf 2-phase) ----------------
// mode 2 (vsq): col<128 -> Cb1[n*128+col] ; 128<=col<192 -> Cb2[n*64+col-128]
// mode 3 (gru): K-range by cb; col<384 -> Cb1[n*384+col] ; else Cb2[n*128+col-384]
__device__ __forceinline__ void gemm_body(
    const unsigned short* __restrict__ A0, const unsigned short* __restrict__ A1,
    const unsigned short* __restrict__ A2, const unsigned short* __restrict__ Bt,
    const float* __restrict__ bias, unsigned short* __restrict__ Cb1,
    unsigned short* __restrict__ Cb2, int Kstride, int Nrows, int mode,
    int swzq, int swzr, int wg) {
    __shared__ unsigned short As[2][128 * 32];
    __shared__ unsigned short Bs[2][128 * 32];
    const int tid = threadIdx.x;
    const int lane = tid & 63;
    const int wave = tid >> 6;          // 0..7
    const int wm = wave >> 2, wn = wave & 3;

    int xcd = wg & 7, pos = wg >> 3;
    int nid = (xcd < swzr) ? xcd * (swzq + 1) + pos
                           : swzr * (swzq + 1) + (xcd - swzr) * swzq + pos;
    int rb, cb, kbeg, kend;
    if (mode == 2) {
        rb = (nid >> 1) * 128;
        cb = (nid & 1) * 128;
        kbeg = 0; kend = 256;
    } else {
        rb = (nid >> 2) * 128;
        cb = (nid & 3) * 128;
        kbeg = (cb == 384) ? 256 : 0;
        kend = (cb == 256) ? 256 : 384;
    }

    const int q0 = wave * 64 + lane;
    const int ar0 = q0 >> 2;
    const int ac0 = ((q0 & 3) ^ ((ar0 >> 1) & 3)) * 8;
    const size_t aoff0 = (size_t)min(rb + ar0, Nrows - 1) * 128 + ac0;
    const size_t boff0 = (size_t)(cb + ar0) * Kstride + ac0;
    const int ldsc0 = (wave * 64) * 8;

#define STAGE(buf, k0s) do {                                              \
        const unsigned short* Ak_ = ((k0s) < 128) ? A0                    \
                                  : ((k0s) < 256) ? A1 : A2;              \
        const int kk_ = (k0s) & 127;                                      \
        gload16(Ak_ + aoff0 + kk_, &As[buf][ldsc0]);                      \
        gload16(Bt + boff0 + (k0s), &Bs[buf][ldsc0]);                     \
    } while (0)

    f32x4 acc[4][2];
#pragma unroll
    for (int i = 0; i < 4; i++)
#pragma unroll
        for (int j = 0; j < 2; j++)
#pragma unroll
            for (int r = 0; r < 4; r++) acc[i][j][r] = 0.f;

    const int r16 = lane & 15;
    const int cof = (((lane >> 4) ^ ((r16 >> 1) & 3)) * 8);

    STAGE(0, kbeg);
    __syncthreads();
    int cur = 0;
    for (int k0 = kbeg; k0 < kend; k0 += 32) {
        if (k0 + 32 < kend) STAGE(cur ^ 1, k0 + 32);
        bf16x8 af[4], bfr[2];
#pragma unroll
        for (int rt = 0; rt < 4; rt++)
            af[rt] = *reinterpret_cast<const bf16x8*>(
                &As[cur][(wm * 64 + rt * 16 + r16) * 32 + cof]);
#pragma unroll
        for (int ct = 0; ct < 2; ct++)
            bfr[ct] = *reinterpret_cast<const bf16x8*>(
                &Bs[cur][(wn * 32 + ct * 16 + r16) * 32 + cof]);
#pragma unroll
        for (int rt = 0; rt < 4; rt++)
#pragma unroll
            for (int ct = 0; ct < 2; ct++)
                acc[rt][ct] = __builtin_amdgcn_mfma_f32_16x16x32_bf16(af[rt], bfr[ct], acc[rt][ct], 0, 0, 0);
        __syncthreads();
        cur ^= 1;
    }
#undef STAGE

#pragma unroll
    for (int rt = 0; rt < 4; rt++) {
#pragma unroll
        for (int ct = 0; ct < 2; ct++) {
            int col = cb + wn * 32 + ct * 16 + r16;
            float bv = bias[col];
#pragma unroll
            for (int r = 0; r < 4; r++) {
                int row = rb + wm * 64 + rt * 16 + (lane >> 4) * 4 + r;
                if (row < Nrows) {
                    float v = acc[rt][ct][r] + bv;
                    if (mode == 2) {
                        if (col < 128) Cb1[(size_t)row * 128 + col] = f2bf(v);
                        else if (col < 192) Cb2[(size_t)row * 64 + (col - 128)] = f2bf(v);
                    } else {
                        if (col < 384) Cb1[(size_t)row * 384 + col] = f2bf(v);
                        else Cb2[(size_t)row * 128 + (col - 384)] = f2bf(v);
                    }
                }
            }
        }
    }
}

__global__ __launch_bounds__(512) void gemm_kernel(
    const unsigned short* __restrict__ A0, const unsigned short* __restrict__ A1,
    const unsigned short* __restrict__ A2, const unsigned short* __restrict__ Bt,
    const float* __restrict__ bias, unsigned short* __restrict__ Cb1,
    unsigned short* __restrict__ Cb2, int Kstride, int Nrows, int mode,
    int swzq, int swzr) {
    gemm_body(A0, A1, A2, Bt, bias, Cb1, Cb2, Kstride, Nrows, mode, swzq, swzr,
              blockIdx.x);
}

// ---- fused round-0 kernel: gemmV + scatter INTERLEAVED 1:2 (co-resident), then fill ----
#define SCAT_B ((NE + 511) / 512)
#define FILL_B ((NN + 7) / 8)
__global__ __launch_bounds__(512) void gemmv_fused(
    const unsigned short* __restrict__ xbf, const unsigned short* __restrict__ hbf,
    const unsigned short* __restrict__ Bvsq, const float* __restrict__ biasv,
    unsigned short* __restrict__ vbf, unsigned short* __restrict__ sqbf,
    int Nrows, int swzq, int swzr, int nwgv,
    const int* __restrict__ src, const int* __restrict__ dst,
    int* __restrict__ cursor, int* __restrict__ ssort,
    const int* __restrict__ rowp, int* __restrict__ dsort) {
    int bid = blockIdx.x;
    const int T = nwgv + SCAT_B;
    if (bid < T) {
        int g = bid / 3, r = bid - g * 3;
        if (r == 0 && g < nwgv) {
            gemm_body(xbf, hbf, hbf, Bvsq, biasv, vbf, sqbf, 256, Nrows, 2,
                      swzq, swzr, g);
            return;
        }
        int sidx = bid - ((g < nwgv) ? (g + (r > 0 ? 1 : 0)) : nwgv);
        int i = sidx * 512 + threadIdx.x;
        if (i < NE) {
            int d = dst[i];
            int slot = atomicAdd(&cursor[d], 1);
            ssort[slot] = src[i];
        }
        return;
    }
    bid -= T;
    int node = bid * 8 + (threadIdx.x >> 6);
    if (node >= NN) return;
    int lane = threadIdx.x & 63;
    int beg = rowp[node], end = rowp[node + 1];
    for (int i = beg + lane; i < end; i += 64) dsort[i] = node;
}

// ---------------- edge dot (bf16 s,q) ----------------
__global__ void edot_kernel(const unsigned short* __restrict__ sqbf,
                            const int* __restrict__ ss, const int* __restrict__ ds,
                            float* __restrict__ eo) {
    int i = blockIdx.x * 256 + threadIdx.x;
    if (i >= NE) return;
    const unsigned short* s = sqbf + (size_t)ss[i] * 64;       // dims 0..31 = sig
    const unsigned short* q = sqbf + (size_t)ds[i] * 64 + 32;  // dims 32..63 = que
    float acc = 0.f;
#pragma unroll
    for (int j = 0; j < 4; j++) {
        uint4 a = reinterpret_cast<const uint4*>(s)[j];
        uint4 b = reinterpret_cast<const uint4*>(q)[j];
        const unsigned int* ap = reinterpret_cast<const unsigned int*>(&a);
        const unsigned int* bp = reinterpret_cast<const unsigned int*>(&b);
#pragma unroll
        for (int w = 0; w < 4; w++) {
            acc += bf2f(ap[w] & 0xffff) * bf2f(bp[w] & 0xffff);
            acc += bf2f(ap[w] >> 16) * bf2f(bp[w] >> 16);
        }
    }
    eo[i] = acc * (1.0f / KEYSZ);
}

// ---------------- per-node softmax + aggregate (round-16 proven: 16 lanes x 4 edges) ----------------
__global__ __launch_bounds__(256) void aggregate_kernel(
    const unsigned short* __restrict__ vbf, float* __restrict__ es,
    const int* __restrict__ ssort, const int* __restrict__ rowp,
    unsigned short* __restrict__ cbf) {
    int lane = threadIdx.x & 63;
    int node = blockIdx.x * 4 + (threadIdx.x >> 6);
    if (node >= NN) return;
    int beg = rowp[node], end = rowp[node + 1];
    if (beg == end) {
        reinterpret_cast<unsigned int*>(cbf + (size_t)node * 128)[lane] = 0u;
        return;
    }
    float m = -1e30f;
    for (int i = beg + lane; i < end; i += 64) m = fmaxf(m, es[i]);
#pragma unroll
    for (int o = 32; o > 0; o >>= 1) m = fmaxf(m, __shfl_xor(m, o));
    float d = 0.f;
    for (int i = beg + lane; i < end; i += 64) {
        float e = __expf(es[i] - m);
        es[i] = e;
        d += e;
    }
#pragma unroll
    for (int o = 32; o > 0; o >>= 1) d += __shfl_xor(d, o);
    float inv = 1.0f / d;
    const int g = lane >> 4, r = lane & 15;
    float a[8];
#pragma unroll
    for (int k = 0; k < 8; k++) a[k] = 0.f;
#pragma unroll 2
    for (int c0 = beg; c0 < end; c0 += 4) {
        int idx = c0 + g;
        if (idx < end) {
            int sj = ssort[idx];
            float w = es[idx] * inv;
            uint4 uv = *reinterpret_cast<const uint4*>(vbf + (size_t)sj * 128 + r * 8);
            a[0] += w * bf2f(uv.x & 0xffff);
            a[1] += w * bf2f(uv.x >> 16);
            a[2] += w * bf2f(uv.y & 0xffff);
            a[3] += w * bf2f(uv.y >> 16);
            a[4] += w * bf2f(uv.z & 0xffff);
            a[5] += w * bf2f(uv.z >> 16);
            a[6] += w * bf2f(uv.w & 0xffff);
            a[7] += w * bf2f(uv.w >> 16);
        }
    }
#pragma unroll
    for (int k = 0; k < 8; k++) {
        a[k] += __shfl_xor(a[k], 16);
        a[k] += __shfl_xor(a[k], 32);
    }
    if (g == 0) {
        uint4 o;
        o.x = (unsigned int)f2bf(a[0]) | ((unsigned int)f2bf(a[1]) << 16);
        o.y = (unsigned int)f2bf(a[2]) | ((unsigned int)f2bf(a[3]) << 16);
        o.z = (unsigned int)f2bf(a[4]) | ((unsigned int)f2bf(a[5]) << 16);
        o.w = (unsigned int)f2bf(a[6]) | ((unsigned int)f2bf(a[7]) << 16);
        *reinterpret_cast<uint4*>(cbf + (size_t)node * 128 + r * 8) = o;
    }
}

// ---------------- GRU elementwise (bf16 h in-place; f32 out only on final round) ----------------
__global__ void gru_kernel(const unsigned short* __restrict__ g,
                           const unsigned short* __restrict__ hn,
                           unsigned short* __restrict__ hio, float* __restrict__ fout) {
    int t = blockIdx.x * 256 + threadIdx.x;
    if (t >= NN * 64) return;
    int n = t >> 6, j2 = (t & 63) * 2;
    const unsigned short* grow = g + (size_t)n * 384;
    unsigned int ur = *reinterpret_cast<const unsigned int*>(grow + j2);
    unsigned int uz = *reinterpret_cast<const unsigned int*>(grow + 128 + j2);
    unsigned int un = *reinterpret_cast<const unsigned int*>(grow + 256 + j2);
    unsigned int uh = *reinterpret_cast<const unsigned int*>(hn + (size_t)n * 128 + j2);
    unsigned int uho = *reinterpret_cast<const unsigned int*>(hio + (size_t)n * 128 + j2);
    float ho0 = bf2f(uho & 0xffff), ho1 = bf2f(uho >> 16);
    float r0 = 1.f / (1.f + __expf(-bf2f(ur & 0xffff)));
    float r1 = 1.f / (1.f + __expf(-bf2f(ur >> 16)));
    float z0 = 1.f / (1.f + __expf(-bf2f(uz & 0xffff)));
    float z1 = 1.f / (1.f + __expf(-bf2f(uz >> 16)));
    float nx0 = bf2f(un & 0xffff) + r0 * bf2f(uh & 0xffff);
    float nx1 = bf2f(un >> 16) + r1 * bf2f(uh >> 16);
    float ng0 = 1.f - 2.f / (__expf(2.f * nx0) + 1.f);
    float ng1 = 1.f - 2.f / (__expf(2.f * nx1) + 1.f);
    float h0 = (1.f - z0) * ng0 + z0 * ho0;
    float h1 = (1.f - z1) * ng1 + z1 * ho1;
    *reinterpret_cast<unsigned int*>(hio + (size_t)n * 128 + j2) =
        (unsigned int)f2bf(h0) | ((unsigned int)f2bf(h1) << 16);
    if (fout)
        *reinterpret_cast<float2*>(fout + (size_t)n * 128 + j2) = make_float2(h0, h1);
}

extern "C" void kernel_launch(void* const* d_in, const int* in_sizes, int n_in,
                              void* d_out, int out_size, void* d_ws, size_t ws_size,
                              hipStream_t stream) {
    const float* x   = (const float*)d_in[0];
    const float* h0  = (const float*)d_in[1];
    const int* src   = (const int*)d_in[2];
    const int* dst   = (const int*)d_in[3];
    const float* Wv  = (const float*)d_in[4];
    const float* bv  = (const float*)d_in[5];
    const float* Wsg = (const float*)d_in[6];
    const float* bsg = (const float*)d_in[7];
    const float* Wq  = (const float*)d_in[8];
    const float* bq  = (const float*)d_in[9];
    const float* Wih = (const float*)d_in[10];
    const float* bih = (const float*)d_in[11];
    const float* Whh = (const float*)d_in[12];
    const float* bhh = (const float*)d_in[13];

    char* ws = (char*)d_ws;
    size_t off = 0;
    auto alloc = [&](size_t bytes) {
        void* p = ws + off;
        off = (off + bytes + 255) & ~(size_t)255;
        return p;
    };
    // region1: vbf[N][128]+sqbf[N][64] (bf16) during attention; gout[N][384] (bf16) after
    unsigned short* vbf = (unsigned short*)alloc((size_t)NN * 384 * 2);
    unsigned short* sqbf = vbf + (size_t)NN * 128;
    unsigned short* gout = vbf;
    float* es = (float*)alloc((size_t)NE * 4);
    int* deg = (int*)alloc(NN * 4);
    int* rowp = (int*)alloc((NN + 1) * 4);
    int* cur = (int*)alloc(NN * 4);
    int* part = (int*)alloc(NB * 4);
    int* boff = (int*)alloc(NB * 4);
    int* ssort = (int*)alloc((size_t)NE * 4);
    int* dsort = (int*)alloc((size_t)NE * 4);
    unsigned short* xbf = (unsigned short*)alloc((size_t)NN * 128 * 2);
    unsigned short* hbf = (unsigned short*)alloc((size_t)NN * 128 * 2);   // h, bf16, in-place
    unsigned short* cnbf = (unsigned short*)alloc((size_t)NN * 128 * 2);  // c (bf16)
    unsigned short* hnbf = (unsigned short*)alloc((size_t)NN * 128 * 2);  // hn (bf16)
    unsigned short* Bvsq = (unsigned short*)alloc(256 * 256 * 2);
    unsigned short* Bgru = (unsigned short*)alloc(512 * 384 * 2);
    float* biasv = (float*)alloc(256 * 4);
    float* biasg = (float*)alloc(512 * 4);

    const int RBK = (NN + 127) / 128;  // 391
    const int NWG_V = RBK * 2, Q_V = NWG_V / 8, R_V = NWG_V % 8;
    const int NWG_G = RBK * 4, Q_G = NWG_G / 8, R_G = NWG_G % 8;

    hipMemsetAsync(deg, 0, NN * 4, stream);
    prep_all<<<(PREP_TOTAL + 255) / 256, 256, 0, stream>>>(
        Wv, Wsg, Wq, bv, bsg, bq, Wih, bih, Whh, bhh, x, h0, dst,
        Bvsq, biasv, Bgru, biasg, xbf, hbf, deg);
    part_kernel<<<NB, 256, 0, stream>>>(deg, part);
    scanp_kernel<<<1, 256, 0, stream>>>(part, boff, rowp);
    scan3_kernel<<<NB, 256, 0, stream>>>(deg, boff, rowp, cur);

    // round 0: gemmV interleaved with CSR scatter (+ dsort fill tail)
    gemmv_fused<<<NWG_V + SCAT_B + FILL_B, 512, 0, stream>>>(
        xbf, hbf, Bvsq, biasv, vbf, sqbf, NN, Q_V, R_V, NWG_V,
        src, dst, cur, ssort, rowp, dsort);
    edot_kernel<<<(NE + 255) / 256, 256, 0, stream>>>(sqbf, ssort, dsort, es);
    aggregate_kernel<<<(NN + 3) / 4, 256, 0, stream>>>(vbf, es, ssort, rowp, cnbf);
    gemm_kernel<<<NWG_G, 512, 0, stream>>>(xbf, cnbf, hbf, Bgru, biasg, gout, hnbf,
                                           384, NN, 3, Q_G, R_G);
    gru_kernel<<<(NN * 64 + 255) / 256, 256, 0, stream>>>(gout, hnbf, hbf, nullptr);

    // round 1
    gemm_kernel<<<NWG_V, 512, 0, stream>>>(xbf, hbf, hbf, Bvsq, biasv, vbf, sqbf,
                                           256, NN, 2, Q_V, R_V);
    edot_kernel<<<(NE + 255) / 256, 256, 0, stream>>>(sqbf, ssort, dsort, es);
    aggregate_kernel<<<(NN + 3) / 4, 256, 0, stream>>>(vbf, es, ssort, rowp, cnbf);
    gemm_kernel<<<NWG_G, 512, 0, stream>>>(xbf, cnbf, hbf, Bgru, biasg, gout, hnbf,
                                           384, NN, 3, Q_G, R_G);
    gru_kernel<<<(NN * 64 + 255) / 256, 256, 0, stream>>>(gout, hnbf, hbf, (float*)d_out);
}